// Round 7
// baseline (117.668 us; speedup 1.0000x reference)
//
#include <hip/hip_runtime.h>
#include <hip/hip_cooperative_groups.h>

namespace cg = cooperative_groups;

// Energy loss over all-pair graph edges.
//   per edge: e = k/2 * (d2 + l^2 - 2*l*sqrt(d2))  ==  k/2 * (sqrt(d2) - l)^2
//
// Structure exploits:
//  - src/dst are the canonical all-pairs pattern: for the r-th edge of row i,
//    dst j = r + (r >= i). src/dst never read from HBM -> only edge_attr
//    (134 MB) streams, as float4 (2 edges / 16 B / lane), 8 loads in flight.
//  - ONE cooperative kernel (partials -> grid.sync -> block 0 finishes).
//    Primary: 1024 blocks (4/CU). Guarded by occupancy query AND error-checked
//    launch; falls back to 512-block coop, then to the proven 2-kernel path.
//  - LDS p[] padded idx+(idx>>2) (5 KB): the dst gather is stride-2 float2;
//    this pad spreads it across ~all 32 banks (~2-way residual = free).

#define NPG   512                       // nodes per graph
#define EPR   (NPG - 1)                 // 511 edges per row
#define EPG   (NPG * EPR)               // 261632 edges per graph
#define ROWS  16                        // rows per chunk
#define CHUNK_EDGES (ROWS * EPR)        // 8176 edges per chunk
#define CHUNK_Q     (CHUNK_EDGES / 2)   // 4088 float4 per chunk

#define LDS_PAD(x) ((x) + ((x) >> 2))

// Two edges in one float4 (l0,k0,l1,k1), le0 even.
// Magic div: floor(x/511) == (x*8209)>>22 for all x <= 8175.
// Edge 1 reuses edge 0's division: row wraps iff r0 == 510.
__device__ __forceinline__ float edge_pair(float4 v, int le0, int row0,
                                           const float2* __restrict__ lds_p)
{
    const int m0 = (le0 * 8209) >> 22;
    const int r0 = le0 - ((m0 << 9) - m0);
    float e;
    {
        const int i = row0 + m0;
        const int j = r0 + (r0 >= i);
        float2 ps = lds_p[LDS_PAD(i)];
        float2 pd = lds_p[LDS_PAD(j)];
        float dx = ps.x - pd.x, dy = ps.y - pd.y;
        float s = __builtin_amdgcn_sqrtf(dx * dx + dy * dy);
        float d = s - v.x;
        e = (0.5f * v.y) * d * d;
    }
    {
        const bool wrap = (r0 == EPR - 1);
        const int i = row0 + m0 + (wrap ? 1 : 0);
        const int r = wrap ? 0 : (r0 + 1);
        const int j = r + (r >= i);
        float2 ps = lds_p[LDS_PAD(i)];
        float2 pd = lds_p[LDS_PAD(j)];
        float dx = ps.x - pd.x, dy = ps.y - pd.y;
        float s = __builtin_amdgcn_sqrtf(dx * dx + dy * dy);
        float d = s - v.z;
        e += (0.5f * v.w) * d * d;
    }
    return e;
}

// Shared worker: block handles CPB chunks of 16 rows. Returns block sum
// (valid on all threads; only thread 0 uses it).
template <int CPB>
__device__ __forceinline__ float block_energy(
    const float2* __restrict__ p2,
    const float2* __restrict__ ea2,
    int b, int t)
{
    const int bpg    = 32 / CPB;           // blocks per graph
    const int g      = b / bpg;
    const int chunk0 = (b % bpg) * CPB;

    __shared__ float2 lds_p[LDS_PAD(NPG - 1) + 4];
    {
        const float2* srcp = p2 + (size_t)g * NPG;
        lds_p[LDS_PAD(t)]       = srcp[t];
        lds_p[LDS_PAD(t + 256)] = srcp[t + 256];
    }
    __syncthreads();

    const float4* gbase = (const float4*)ea2 + (size_t)g * (EPG / 2);

    float acc = 0.0f;

#pragma unroll
    for (int ch = 0; ch < CPB; ++ch) {
        const int row0 = (chunk0 + ch) * ROWS;
        const float4* ea4 = gbase + (size_t)(chunk0 + ch) * CHUNK_Q;

#pragma unroll
        for (int s = 0; s < 2; ++s) {
            // 8 independent 16B loads in flight (static indices -> registers)
            float4 v[8];
            int    qc[8];
#pragma unroll
            for (int k = 0; k < 8; ++k) {
                const int qq = t + s * 2048 + k * 256;
                qc[k] = (qq < CHUNK_Q) ? qq : (CHUNK_Q - 1);  // clamp in-range
                v[k] = ea4[qc[k]];
            }
#pragma unroll
            for (int k = 0; k < 8; ++k) {
                float e = edge_pair(v[k], 2 * qc[k], row0, lds_p);
                acc += (t + s * 2048 + k * 256 < CHUNK_Q) ? e : 0.0f;
            }
        }
    }

    for (int off = 32; off > 0; off >>= 1)
        acc += __shfl_down(acc, off, 64);

    __shared__ float wsum[4];
    if ((t & 63) == 0) wsum[t >> 6] = acc;
    __syncthreads();

    return wsum[0] + wsum[1] + wsum[2] + wsum[3];
}

template <int CPB, int MINWAVES>
__global__ __launch_bounds__(256, MINWAVES) void energy_coop(
    const float2* __restrict__ p2,
    const float2* __restrict__ ea2,
    float* __restrict__ partial,
    float* __restrict__ out)
{
    const int nblk = 64 * (32 / CPB);
    const int b = blockIdx.x;
    const int t = threadIdx.x;

    float bsum = block_energy<CPB>(p2, ea2, b, t);
    if (t == 0)
        __hip_atomic_store(&partial[b], bsum, __ATOMIC_RELEASE,
                           __HIP_MEMORY_SCOPE_AGENT);

    cg::this_grid().sync();

    if (b == 0) {
        float a = 0.0f;
#pragma unroll
        for (int u = 0; u < 4; ++u) {
            const int idx = t * 4 + u;
            if (idx < nblk)
                a += __hip_atomic_load(&partial[idx], __ATOMIC_RELAXED,
                                       __HIP_MEMORY_SCOPE_AGENT);
        }
        for (int off = 32; off > 0; off >>= 1)
            a += __shfl_down(a, off, 64);

        __shared__ float fsum[4];
        if ((t & 63) == 0) fsum[t >> 6] = a;
        __syncthreads();
        if (t == 0)
            out[0] = fsum[0] + fsum[1] + fsum[2] + fsum[3];
    }
}

// ---- fallback path (proven two-kernel structure) ----

__global__ __launch_bounds__(256, 2) void energy_main(
    const float2* __restrict__ p2,
    const float2* __restrict__ ea2,
    float* __restrict__ partial)
{
    float bsum = block_energy<4>(p2, ea2, blockIdx.x, threadIdx.x);
    if (threadIdx.x == 0)
        partial[blockIdx.x] = bsum;
}

__global__ __launch_bounds__(256) void energy_finish(
    const float4* __restrict__ partial4,
    float* __restrict__ out)
{
    const int t = threadIdx.x;
    float a = 0.0f;
    if (t < 128) {
        float4 v = partial4[t];
        a = (v.x + v.y) + (v.z + v.w);
    }
    for (int off = 32; off > 0; off >>= 1)
        a += __shfl_down(a, off, 64);

    __shared__ float fsum[4];
    if ((t & 63) == 0) fsum[t >> 6] = a;
    __syncthreads();
    if (t == 0)
        out[0] = fsum[0] + fsum[1] + fsum[2] + fsum[3];
}

extern "C" void kernel_launch(void* const* d_in, const int* in_sizes, int n_in,
                              void* d_out, int out_size, void* d_ws, size_t ws_size,
                              hipStream_t stream) {
    const float2* p2  = (const float2*)d_in[0];
    const float2* ea2 = (const float2*)d_in[1];
    float* out     = (float*)d_out;
    float* partial = (float*)d_ws;     // <= 1024 floats = 4 KB scratch

    // Capture-safe host-side queries (no stream ops, deterministic).
    int dev = 0;
    hipGetDevice(&dev);
    int coopAttr = 0;
    hipDeviceGetAttribute(&coopAttr, hipDeviceAttributeCooperativeLaunch, dev);
    int numCU = 0;
    hipDeviceGetAttribute(&numCU, hipDeviceAttributeMultiprocessorCount, dev);

    if (coopAttr) {
        // Primary: 1024 blocks, 2 chunks each, 4 blocks/CU.
        int maxBlk = 0;
        hipOccupancyMaxActiveBlocksPerMultiprocessor(
            &maxBlk, energy_coop<2, 4>, 256, 0);
        if ((long)maxBlk * numCU >= 1024) {
            void* args[] = { (void*)&p2, (void*)&ea2, (void*)&partial, (void*)&out };
            hipError_t err = hipLaunchCooperativeKernel(
                (const void*)energy_coop<2, 4>, dim3(1024), dim3(256),
                args, 0, stream);
            if (err == hipSuccess) return;
        }
        // Secondary: 512 blocks, 4 chunks each (round-6 proven config).
        hipOccupancyMaxActiveBlocksPerMultiprocessor(
            &maxBlk, energy_coop<4, 2>, 256, 0);
        if ((long)maxBlk * numCU >= 512) {
            void* args[] = { (void*)&p2, (void*)&ea2, (void*)&partial, (void*)&out };
            hipError_t err = hipLaunchCooperativeKernel(
                (const void*)energy_coop<4, 2>, dim3(512), dim3(256),
                args, 0, stream);
            if (err == hipSuccess) return;
        }
    }

    // Fallback: proven two-kernel path.
    energy_main<<<512, 256, 0, stream>>>(p2, ea2, partial);
    energy_finish<<<1, 256, 0, stream>>>((const float4*)partial, out);
}

// Round 8
// 113.346 us; speedup vs baseline: 1.0381x; 1.0381x over previous
//
#include <hip/hip_runtime.h>
#include <hip/hip_cooperative_groups.h>

namespace cg = cooperative_groups;

// Energy loss over all-pair graph edges.
//   per edge: e = k/2 * (d2 + l^2 - 2*l*sqrt(d2))  ==  k/2 * (sqrt(d2) - l)^2
//
// Structure exploits:
//  - src/dst are the canonical all-pairs pattern: for the r-th edge of row i,
//    dst j = r + (r >= i). src/dst never read from HBM -> only edge_attr
//    (134 MB) streams, as float4 (2 edges / 16 B / lane), 4 loads in flight.
//  - ONE cooperative kernel (partials -> grid.sync -> block 0 finishes).
//    Body is the round-6-proven 4-deep version with __launch_bounds__(256,2)
//    (84 VGPR; round-7 showed minwaves=4's 64-VGPR cap serializes the loads).
//    Primary 1024 blocks (4/CU, margin: 6/CU fit), secondary 512 (proven),
//    fallback two-kernel. All launches guarded + error-checked.
//  - LDS p[] padded idx+(idx>>2): stride-2 float2 gather spreads over all
//    banks (measured: conflicts 946K -> 581K vs the >>4 pad).

#define NPG   512                       // nodes per graph
#define EPR   (NPG - 1)                 // 511 edges per row
#define EPG   (NPG * EPR)               // 261632 edges per graph
#define ROWS  16                        // rows per chunk
#define CHUNK_EDGES (ROWS * EPR)        // 8176 edges per chunk
#define CHUNK_Q     (CHUNK_EDGES / 2)   // 4088 float4 per chunk

#define LDS_PAD(x) ((x) + ((x) >> 2))

// Two edges in one float4 (l0,k0,l1,k1), le0 even.
// Magic div: floor(x/511) == (x*8209)>>22 for all x <= 8175.
// Edge 1 reuses edge 0's division: row wraps iff r0 == 510.
__device__ __forceinline__ float edge_pair(float4 v, int le0, int row0,
                                           const float2* __restrict__ lds_p)
{
    const int m0 = (le0 * 8209) >> 22;
    const int r0 = le0 - ((m0 << 9) - m0);
    float e;
    {
        const int i = row0 + m0;
        const int j = r0 + (r0 >= i);
        float2 ps = lds_p[LDS_PAD(i)];
        float2 pd = lds_p[LDS_PAD(j)];
        float dx = ps.x - pd.x, dy = ps.y - pd.y;
        float s = __builtin_amdgcn_sqrtf(dx * dx + dy * dy);
        float d = s - v.x;
        e = (0.5f * v.y) * d * d;
    }
    {
        const bool wrap = (r0 == EPR - 1);
        const int i = row0 + m0 + (wrap ? 1 : 0);
        const int r = wrap ? 0 : (r0 + 1);
        const int j = r + (r >= i);
        float2 ps = lds_p[LDS_PAD(i)];
        float2 pd = lds_p[LDS_PAD(j)];
        float dx = ps.x - pd.x, dy = ps.y - pd.y;
        float s = __builtin_amdgcn_sqrtf(dx * dx + dy * dy);
        float d = s - v.z;
        e += (0.5f * v.w) * d * d;
    }
    return e;
}

// Round-6-proven worker body: CPB chunks of 16 rows, 4 independent float4
// loads in flight per step. Returns block sum (valid on all threads).
template <int CPB>
__device__ __forceinline__ float block_energy(
    const float2* __restrict__ p2,
    const float2* __restrict__ ea2,
    int b, int t)
{
    const int bpg    = 32 / CPB;           // blocks per graph (CPB divides 32)
    const int g      = b / bpg;
    const int chunk0 = (b % bpg) * CPB;

    __shared__ float2 lds_p[LDS_PAD(NPG - 1) + 4];
    {
        const float2* srcp = p2 + (size_t)g * NPG;
        lds_p[LDS_PAD(t)]       = srcp[t];
        lds_p[LDS_PAD(t + 256)] = srcp[t + 256];
    }
    __syncthreads();

    const float4* gbase = (const float4*)ea2 + (size_t)g * (EPG / 2);

    float acc = 0.0f;

#pragma unroll
    for (int ch = 0; ch < CPB; ++ch) {
        const int row0 = (chunk0 + ch) * ROWS;
        const float4* ea4 = gbase + (size_t)(chunk0 + ch) * CHUNK_Q;

#pragma unroll
        for (int s = 0; s < 4; ++s) {
            const int q0 = t + s * 1024;
            const int q1 = q0 + 256;
            const int q2 = q0 + 512;
            const int q3 = q0 + 768;
            const bool ok3 = (q3 < CHUNK_Q);          // only s==3 overflows
            const int q3c = ok3 ? q3 : (CHUNK_Q - 1); // clamp, stays in range

            // 4 independent 16B loads in flight
            float4 v0 = ea4[q0];
            float4 v1 = ea4[q1];
            float4 v2 = ea4[q2];
            float4 v3 = ea4[q3c];

            acc += edge_pair(v0, 2 * q0, row0, lds_p);
            acc += edge_pair(v1, 2 * q1, row0, lds_p);
            acc += edge_pair(v2, 2 * q2, row0, lds_p);
            float e3 = edge_pair(v3, 2 * q3c, row0, lds_p);
            acc += ok3 ? e3 : 0.0f;
        }
    }

    for (int off = 32; off > 0; off >>= 1)
        acc += __shfl_down(acc, off, 64);

    __shared__ float wsum[4];
    if ((t & 63) == 0) wsum[t >> 6] = acc;
    __syncthreads();

    return wsum[0] + wsum[1] + wsum[2] + wsum[3];
}

template <int CPB>
__global__ __launch_bounds__(256, 2) void energy_coop(
    const float2* __restrict__ p2,
    const float2* __restrict__ ea2,
    float* __restrict__ partial,
    float* __restrict__ out)
{
    const int nblk = 64 * (32 / CPB);
    const int b = blockIdx.x;
    const int t = threadIdx.x;

    float bsum = block_energy<CPB>(p2, ea2, b, t);
    if (t == 0)
        __hip_atomic_store(&partial[b], bsum, __ATOMIC_RELEASE,
                           __HIP_MEMORY_SCOPE_AGENT);

    cg::this_grid().sync();

    if (b == 0) {
        float a = 0.0f;
#pragma unroll
        for (int u = 0; u < 4; ++u) {
            const int idx = t * 4 + u;
            if (idx < nblk)
                a += __hip_atomic_load(&partial[idx], __ATOMIC_RELAXED,
                                       __HIP_MEMORY_SCOPE_AGENT);
        }
        for (int off = 32; off > 0; off >>= 1)
            a += __shfl_down(a, off, 64);

        __shared__ float fsum[4];
        if ((t & 63) == 0) fsum[t >> 6] = a;
        __syncthreads();
        if (t == 0)
            out[0] = fsum[0] + fsum[1] + fsum[2] + fsum[3];
    }
}

// ---- fallback path (two-kernel structure, 2048 blocks) ----

__global__ __launch_bounds__(256, 2) void energy_main(
    const float2* __restrict__ p2,
    const float2* __restrict__ ea2,
    float* __restrict__ partial)
{
    float bsum = block_energy<1>(p2, ea2, blockIdx.x, threadIdx.x);
    if (threadIdx.x == 0)
        partial[blockIdx.x] = bsum;
}

__global__ __launch_bounds__(256) void energy_finish(
    const float4* __restrict__ partial4,
    float* __restrict__ out,
    int nquad)  // number of float4 partial quads
{
    const int t = threadIdx.x;
    float a = 0.0f;
    for (int i = t; i < nquad; i += 256) {
        float4 v = partial4[i];
        a += (v.x + v.y) + (v.z + v.w);
    }
    for (int off = 32; off > 0; off >>= 1)
        a += __shfl_down(a, off, 64);

    __shared__ float fsum[4];
    if ((t & 63) == 0) fsum[t >> 6] = a;
    __syncthreads();
    if (t == 0)
        out[0] = fsum[0] + fsum[1] + fsum[2] + fsum[3];
}

extern "C" void kernel_launch(void* const* d_in, const int* in_sizes, int n_in,
                              void* d_out, int out_size, void* d_ws, size_t ws_size,
                              hipStream_t stream) {
    const float2* p2  = (const float2*)d_in[0];
    const float2* ea2 = (const float2*)d_in[1];
    float* out     = (float*)d_out;
    float* partial = (float*)d_ws;     // <= 2048 floats = 8 KB scratch

    // Capture-safe host-side queries (no stream ops, deterministic).
    int dev = 0;
    hipGetDevice(&dev);
    int coopAttr = 0;
    hipDeviceGetAttribute(&coopAttr, hipDeviceAttributeCooperativeLaunch, dev);
    int numCU = 0;
    hipDeviceGetAttribute(&numCU, hipDeviceAttributeMultiprocessorCount, dev);

    if (coopAttr) {
        // Primary: 1024 blocks, 2 chunks each (needs 4/CU; ~6/CU fit at 84 VGPR).
        int maxBlk = 0;
        hipOccupancyMaxActiveBlocksPerMultiprocessor(
            &maxBlk, energy_coop<2>, 256, 0);
        if ((long)maxBlk * numCU >= 1024) {
            void* args[] = { (void*)&p2, (void*)&ea2, (void*)&partial, (void*)&out };
            hipError_t err = hipLaunchCooperativeKernel(
                (const void*)energy_coop<2>, dim3(1024), dim3(256),
                args, 0, stream);
            if (err == hipSuccess) return;
        }
        // Secondary: 512 blocks, 4 chunks each (round-6 proven, 26.9 us).
        hipOccupancyMaxActiveBlocksPerMultiprocessor(
            &maxBlk, energy_coop<4>, 256, 0);
        if ((long)maxBlk * numCU >= 512) {
            void* args[] = { (void*)&p2, (void*)&ea2, (void*)&partial, (void*)&out };
            hipError_t err = hipLaunchCooperativeKernel(
                (const void*)energy_coop<4>, dim3(512), dim3(256),
                args, 0, stream);
            if (err == hipSuccess) return;
        }
    }

    // Fallback: two-kernel path, full occupancy streaming.
    energy_main<<<2048, 256, 0, stream>>>(p2, ea2, partial);
    energy_finish<<<1, 256, 0, stream>>>((const float4*)partial, out, 2048 / 4);
}

// Round 9
// 28.333 us; speedup vs baseline: 4.1530x; 4.0005x over previous
//
#include <hip/hip_runtime.h>

// Energy loss over all-pair graph edges.
//   per edge: e = k/2 * (d2 + l^2 - 2*l*sqrt(d2))  ==  k/2 * (sqrt(d2) - l)^2
//
// Structure exploits:
//  - src/dst are the canonical all-pairs pattern: for the r-th edge of row i,
//    dst j = r + (r >= i). src/dst never read from HBM -> only edge_attr
//    (134 MB) streams as float4 (2 edges / 16 B / lane).
//  - 2048 blocks x 1 chunk (16 rows): ~6 blocks/CU co-resident, 8 named
//    float4 loads in flight per thread -> ~100+ KB outstanding per CU, fully
//    covering ~900 ns HBM latency (rounds 6-8 showed 2 blocks/CU x 4-deep was
//    latency-bound; 1024-block coop hit a codegen cliff twice -> abandoned).
//  - PARITY-SPLIT LDS for p: idx(j) = j/2 + (j&1)*260. The dst gather is
//    stride-2 in j across lanes (8-way bank alias with linear layout, 946K
//    conflicts measured; additive pads only smear it to 581K). Parity split
//    makes both the even-r and odd-r gathers lane-stride-1 = conflict-free.
//  - Two-kernel finish (proven): block partials to d_ws, 1-block reduce.

#define NPG   512                       // nodes per graph
#define EPR   (NPG - 1)                 // 511 edges per row
#define EPG   (NPG * EPR)               // 261632 edges per graph
#define ROWS  16                        // rows per chunk
#define CHUNK_EDGES (ROWS * EPR)        // 8176 edges per chunk
#define CHUNK_Q     (CHUNK_EDGES / 2)   // 4088 float4 per chunk
#define NBLK  2048                      // 32 chunks/graph x 64 graphs

__device__ __forceinline__ int pidx(int j) {
    return (j >> 1) + (j & 1) * 260;    // even j -> [0,256), odd j -> [260,516)
}

// Two edges in one float4 (l0,k0,l1,k1), le0 even.
// Magic div: floor(x/511) == (x*8209)>>22 for all x <= 8175.
// Edge 1 reuses edge 0's division: row wraps iff r0 == 510.
__device__ __forceinline__ float edge_pair(float4 v, int le0, int row0,
                                           const float2* __restrict__ lds_p)
{
    const int m0 = (le0 * 8209) >> 22;
    const int r0 = le0 - ((m0 << 9) - m0);
    float e;
    {
        const int i = row0 + m0;
        const int j = r0 + (r0 >= i);
        float2 ps = lds_p[pidx(i)];
        float2 pd = lds_p[pidx(j)];
        float dx = ps.x - pd.x, dy = ps.y - pd.y;
        float s = __builtin_amdgcn_sqrtf(dx * dx + dy * dy);
        float d = s - v.x;
        e = (0.5f * v.y) * d * d;
    }
    {
        const bool wrap = (r0 == EPR - 1);
        const int i = row0 + m0 + (wrap ? 1 : 0);
        const int r = wrap ? 0 : (r0 + 1);
        const int j = r + (r >= i);
        float2 ps = lds_p[pidx(i)];
        float2 pd = lds_p[pidx(j)];
        float dx = ps.x - pd.x, dy = ps.y - pd.y;
        float s = __builtin_amdgcn_sqrtf(dx * dx + dy * dy);
        float d = s - v.z;
        e += (0.5f * v.w) * d * d;
    }
    return e;
}

__global__ __launch_bounds__(256) void energy_main(
    const float2* __restrict__ p2,
    const float2* __restrict__ ea2,
    float* __restrict__ partial)
{
    const int b = blockIdx.x;
    const int t = threadIdx.x;
    const int g     = b >> 5;           // 32 chunks per graph
    const int chunk = b & 31;
    const int row0  = chunk * ROWS;

    __shared__ float2 lds_p[520];       // parity-split, max idx 515
    {
        const float2* srcp = p2 + (size_t)g * NPG;
        lds_p[pidx(t)]       = srcp[t];
        lds_p[pidx(t + 256)] = srcp[t + 256];
    }
    __syncthreads();

    const float4* ea4 = (const float4*)ea2 +
                        ((size_t)g * (EPG / 2) + (size_t)chunk * CHUNK_Q);

    float acc = 0.0f;

    // ---- batch 0: q = t + {0,256,...,1792} — all < 4088, 8 loads in flight
    {
        float4 v0 = ea4[t];
        float4 v1 = ea4[t + 256];
        float4 v2 = ea4[t + 512];
        float4 v3 = ea4[t + 768];
        float4 v4 = ea4[t + 1024];
        float4 v5 = ea4[t + 1280];
        float4 v6 = ea4[t + 1536];
        float4 v7 = ea4[t + 1792];
        acc += edge_pair(v0, 2 * t,          row0, lds_p);
        acc += edge_pair(v1, 2 * (t + 256),  row0, lds_p);
        acc += edge_pair(v2, 2 * (t + 512),  row0, lds_p);
        acc += edge_pair(v3, 2 * (t + 768),  row0, lds_p);
        acc += edge_pair(v4, 2 * (t + 1024), row0, lds_p);
        acc += edge_pair(v5, 2 * (t + 1280), row0, lds_p);
        acc += edge_pair(v6, 2 * (t + 1536), row0, lds_p);
        acc += edge_pair(v7, 2 * (t + 1792), row0, lds_p);
    }
    // ---- batch 1: q = t + {2048,...,3840} — only the last can exceed 4087
    {
        const int q7 = t + 3840;
        const bool ok7 = (q7 < CHUNK_Q);
        const int q7c = ok7 ? q7 : (CHUNK_Q - 1);   // clamp, stays in range

        float4 v0 = ea4[t + 2048];
        float4 v1 = ea4[t + 2304];
        float4 v2 = ea4[t + 2560];
        float4 v3 = ea4[t + 2816];
        float4 v4 = ea4[t + 3072];
        float4 v5 = ea4[t + 3328];
        float4 v6 = ea4[t + 3584];
        float4 v7 = ea4[q7c];
        acc += edge_pair(v0, 2 * (t + 2048), row0, lds_p);
        acc += edge_pair(v1, 2 * (t + 2304), row0, lds_p);
        acc += edge_pair(v2, 2 * (t + 2560), row0, lds_p);
        acc += edge_pair(v3, 2 * (t + 2816), row0, lds_p);
        acc += edge_pair(v4, 2 * (t + 3072), row0, lds_p);
        acc += edge_pair(v5, 2 * (t + 3328), row0, lds_p);
        acc += edge_pair(v6, 2 * (t + 3584), row0, lds_p);
        float e7 = edge_pair(v7, 2 * q7c,    row0, lds_p);
        acc += ok7 ? e7 : 0.0f;
    }

    // wave-64 reduce, cross-wave via LDS, one plain store per block
    for (int off = 32; off > 0; off >>= 1)
        acc += __shfl_down(acc, off, 64);

    __shared__ float wsum[4];
    if ((t & 63) == 0) wsum[t >> 6] = acc;
    __syncthreads();

    if (t == 0)
        partial[b] = wsum[0] + wsum[1] + wsum[2] + wsum[3];
}

__global__ __launch_bounds__(256) void energy_finish(
    const float4* __restrict__ partial4,
    float* __restrict__ out)
{
    const int t = threadIdx.x;
    float4 a = partial4[t];
    float4 b = partial4[t + 256];
    float acc = ((a.x + a.y) + (a.z + a.w)) + ((b.x + b.y) + (b.z + b.w));

    for (int off = 32; off > 0; off >>= 1)
        acc += __shfl_down(acc, off, 64);

    __shared__ float fsum[4];
    if ((t & 63) == 0) fsum[t >> 6] = acc;
    __syncthreads();
    if (t == 0)
        out[0] = fsum[0] + fsum[1] + fsum[2] + fsum[3];
}

extern "C" void kernel_launch(void* const* d_in, const int* in_sizes, int n_in,
                              void* d_out, int out_size, void* d_ws, size_t ws_size,
                              hipStream_t stream) {
    const float2* p2  = (const float2*)d_in[0];
    const float2* ea2 = (const float2*)d_in[1];
    float* out     = (float*)d_out;
    float* partial = (float*)d_ws;     // 2048 floats = 8 KB scratch

    energy_main<<<NBLK, 256, 0, stream>>>(p2, ea2, partial);
    energy_finish<<<1, 256, 0, stream>>>((const float4*)partial, out);
}